// Round 1
// baseline (102.829 us; speedup 1.0000x reference)
//
#include <hip/hip_runtime.h>
#include <math.h>

// out_i = clamp(out_{i-1}; a_i, a_i+1)  with a_i = inputs_i * k.
// Clamp functions are closed under composition -> parallel scan.

#define TPB 256
#define PER_THREAD 32
#define CHUNK (TPB * PER_THREAD)   // 8192 elements per block
#define TPB2 256

__device__ __forceinline__ void comp_apply(float& lo, float& hi, float a, float b) {
    // F := clamp(.; a,b) ∘ F
    lo = fminf(fmaxf(lo, a), b);
    hi = fminf(fmaxf(hi, a), b);
}

// ---------------- Pass 1: per-block composed clamp aggregate ----------------
__global__ __launch_bounds__(TPB) void pass1(const float* __restrict__ x,
                                             const float* __restrict__ kern,
                                             float2* __restrict__ agg) {
    const float k = kern[0];
    const int t = threadIdx.x;
    const size_t base = ((size_t)blockIdx.x * TPB + (size_t)t) * PER_THREAD;
    const float4* p = reinterpret_cast<const float4*>(x + base);

    float lo = -INFINITY, hi = INFINITY;   // identity clamp
#pragma unroll
    for (int i = 0; i < PER_THREAD / 4; ++i) {
        float4 v = p[i];
        float a;
        a = v.x * k; comp_apply(lo, hi, a, a + 1.0f);
        a = v.y * k; comp_apply(lo, hi, a, a + 1.0f);
        a = v.z * k; comp_apply(lo, hi, a, a + 1.0f);
        a = v.w * k; comp_apply(lo, hi, a, a + 1.0f);
    }

    // Ordered wave reduce: lane i combines [i, i+off) (self, FIRST) with
    // lane i+off's segment (SECOND). Out-of-range shfl returns self; clamp
    // self-compose is idempotent, so that's harmless. Lane 0 ends with [0,64).
#pragma unroll
    for (int off = 1; off < 64; off <<= 1) {
        float plo = __shfl_down(lo, off);
        float phi_ = __shfl_down(hi, off);
        float nlo = fminf(fmaxf(lo, plo), phi_);
        float nhi = fminf(fmaxf(hi, plo), phi_);
        lo = nlo; hi = nhi;
    }

    __shared__ float wlo[TPB / 64], whi[TPB / 64];
    const int w = t >> 6, lane = t & 63;
    if (lane == 0) { wlo[w] = lo; whi[w] = hi; }
    __syncthreads();
    if (t == 0) {
        float L = wlo[0], H = whi[0];
#pragma unroll
        for (int i = 1; i < TPB / 64; ++i) {
            L = fminf(fmaxf(L, wlo[i]), whi[i]);
            H = fminf(fmaxf(H, wlo[i]), whi[i]);
        }
        agg[blockIdx.x] = make_float2(L, H);
    }
}

// ---------------- Pass 2: scan block aggregates -> per-block entry value ---
__global__ __launch_bounds__(TPB2) void pass2(const float2* __restrict__ agg,
                                              const float* __restrict__ state,
                                              float* __restrict__ ventry,
                                              float* __restrict__ out_last,
                                              int nblocks) {
    const int t = threadIdx.x;
    const int per = nblocks / TPB2;   // 4 for T=2^23

    float lo = -INFINITY, hi = INFINITY;
    for (int j = 0; j < per; ++j) {
        float2 ag = agg[t * per + j];
        lo = fminf(fmaxf(lo, ag.x), ag.y);
        hi = fminf(fmaxf(hi, ag.x), ag.y);
    }

    __shared__ float slo[TPB2], shi[TPB2];
    slo[t] = lo; shi[t] = hi;
    __syncthreads();
    // Hillis-Steele inclusive scan (prefix FIRST, self SECOND)
    for (int off = 1; off < TPB2; off <<= 1) {
        float plo = -INFINITY, phi_ = INFINITY;
        if (t >= off) { plo = slo[t - off]; phi_ = shi[t - off]; }
        __syncthreads();
        float nlo = fminf(fmaxf(plo, lo), hi);
        float nhi = fminf(fmaxf(phi_, lo), hi);
        lo = nlo; hi = nhi;
        slo[t] = lo; shi[t] = hi;
        __syncthreads();
    }

    // exclusive prefix for this thread's group of aggregates
    float elo = -INFINITY, ehi = INFINITY;
    if (t > 0) { elo = slo[t - 1]; ehi = shi[t - 1]; }

    float v = state[0];
    v = fminf(fmaxf(v, elo), ehi);
    for (int j = 0; j < per; ++j) {
        float2 ag = agg[t * per + j];
        ventry[t * per + j] = v;
        v = fminf(fmaxf(v, ag.x), ag.y);
    }
    if (t == TPB2 - 1) *out_last = v;   // new_state = last output
}

// ---------------- Pass 3: produce outputs ----------------------------------
__global__ __launch_bounds__(TPB) void pass3(const float* __restrict__ x,
                                             const float* __restrict__ kern,
                                             const float* __restrict__ ventry,
                                             float* __restrict__ out) {
    const float k = kern[0];
    const int t = threadIdx.x;
    const size_t base = ((size_t)blockIdx.x * TPB + (size_t)t) * PER_THREAD;
    const float4* p = reinterpret_cast<const float4*>(x + base);

    float4 d[PER_THREAD / 4];
    float lo = -INFINITY, hi = INFINITY;
#pragma unroll
    for (int i = 0; i < PER_THREAD / 4; ++i) {
        d[i] = p[i];
        float a;
        a = d[i].x * k; comp_apply(lo, hi, a, a + 1.0f);
        a = d[i].y * k; comp_apply(lo, hi, a, a + 1.0f);
        a = d[i].z * k; comp_apply(lo, hi, a, a + 1.0f);
        a = d[i].w * k; comp_apply(lo, hi, a, a + 1.0f);
    }

    const int lane = t & 63, w = t >> 6;
    // wave inclusive scan (prefix FIRST, self SECOND)
#pragma unroll
    for (int off = 1; off < 64; off <<= 1) {
        float plo = __shfl_up(lo, off);
        float phi_ = __shfl_up(hi, off);
        if (lane >= off) {
            float nlo = fminf(fmaxf(plo, lo), hi);
            float nhi = fminf(fmaxf(phi_, lo), hi);
            lo = nlo; hi = nhi;
        }
    }
    // wave-exclusive from inclusive
    float elo = __shfl_up(lo, 1);
    float ehi = __shfl_up(hi, 1);
    if (lane == 0) { elo = -INFINITY; ehi = INFINITY; }

    __shared__ float wlo[TPB / 64], whi[TPB / 64];
    if (lane == 63) { wlo[w] = lo; whi[w] = hi; }
    __syncthreads();

    float v = ventry[blockIdx.x];
    for (int i = 0; i < w; ++i)                 // apply earlier waves' totals
        v = fminf(fmaxf(v, wlo[i]), whi[i]);
    v = fminf(fmaxf(v, elo), ehi);              // apply wave-exclusive prefix

    float4* o = reinterpret_cast<float4*>(out + base);
#pragma unroll
    for (int i = 0; i < PER_THREAD / 4; ++i) {
        float a, b; float4 r;
        a = d[i].x * k; b = a + 1.0f; v = fminf(fmaxf(v, a), b); r.x = v;
        a = d[i].y * k; b = a + 1.0f; v = fminf(fmaxf(v, a), b); r.y = v;
        a = d[i].z * k; b = a + 1.0f; v = fminf(fmaxf(v, a), b); r.z = v;
        a = d[i].w * k; b = a + 1.0f; v = fminf(fmaxf(v, a), b); r.w = v;
        o[i] = r;
    }
}

extern "C" void kernel_launch(void* const* d_in, const int* in_sizes, int n_in,
                              void* d_out, int out_size, void* d_ws, size_t ws_size,
                              hipStream_t stream) {
    const float* x     = (const float*)d_in[0];   // inputs [1,T]
    const float* state = (const float*)d_in[1];   // [1,1]
    const float* kern  = (const float*)d_in[2];   // [1,1]
    float* out = (float*)d_out;                   // T outputs + 1 new_state

    const size_t T = (size_t)in_sizes[0];
    const int nblocks = (int)(T / CHUNK);         // 1024 for T=2^23

    float2* agg   = (float2*)d_ws;
    float* ventry = (float*)((char*)d_ws + (size_t)nblocks * sizeof(float2));

    pass1<<<nblocks, TPB, 0, stream>>>(x, kern, agg);
    pass2<<<1, TPB2, 0, stream>>>(agg, state, ventry, out + T, nblocks);
    pass3<<<nblocks, TPB, 0, stream>>>(x, kern, ventry, out);
}